// Round 4
// baseline (88.075 us; speedup 1.0000x reference)
//
#include <hip/hip_runtime.h>
#include <math.h>

#define BB 8
#define TT 4096
#define NE 512
#define DD 64

using f32x4 = __attribute__((ext_vector_type(4))) float;
using s16x8 = __attribute__((ext_vector_type(8))) short;

#define EXP2 __builtin_amdgcn_exp2f

__device__ __forceinline__ ushort f2bf(float f) {
  uint u = __builtin_bit_cast(uint, f);
  u += 0x7fffu + ((u >> 16) & 1u);
  return (ushort)(u >> 16);
}
__device__ __forceinline__ uint cvtpk(float lo, float hi) {
  uint r;
  asm("v_cvt_pk_bf16_f32 %0, %1, %2" : "=v"(r) : "v"(lo), "v"(hi));
  return r;
}

#define KTSWZ(d) ((((d) ^ ((d) >> 3)) & 7) << 4)

// ---- prep: WT[col][k] bf16; col<64 = wq * 0.125*log2(e)  (exp2 domain), else wk
__global__ __launch_bounds__(256) void prep_kernel(
    const float* __restrict__ wq, const float* __restrict__ wk,
    ushort* __restrict__ WT) {
  const int i = blockIdx.x * 256 + threadIdx.x;  // 65536
  const int col = i & 127, k = i >> 7;
  const float v = (col < DD) ? wq[(size_t)k * DD + col] * 0.18033688f
                             : wk[(size_t)k * DD + (col - DD)];
  WT[(size_t)col * NE + k] = f2bf(v);
}

// ---- proj: bf16 MFMA GEMM, out = x @ [wq*s | wk] ----------------------------
__global__ __launch_bounds__(256) void proj_kernel(
    const float* __restrict__ x, const ushort* __restrict__ WT,
    ushort* __restrict__ Qo, ushort* __restrict__ Ko) {
  __shared__ __align__(16) char smem[24576];
  char* As = smem;          // [64 rows][128B] swizzled
  char* Bs = smem + 8192;   // [128 cols][128B] swizzled
  const int t = threadIdx.x;
  const int w = t >> 6, l = t & 63;
  const int lm = l & 15, lg = l >> 4;
  const int wr = w >> 1, wc = w & 1;
  const size_t rbase = (size_t)blockIdx.x * 64;

  const int arow = t >> 2, akq = (t & 3) * 16;
  const int bcol = t >> 1, bkh = (t & 1) * 32;

  f32x4 acc[2][4];
#pragma unroll
  for (int mt = 0; mt < 2; ++mt)
#pragma unroll
    for (int nt = 0; nt < 4; ++nt) acc[mt][nt] = (f32x4)0.f;

  float4 xa0, xa1, xa2, xa3;
  uint4 wb0, wb1, wb2, wb3;
  {
    const float* xp = x + (rbase + arow) * NE + akq;
    xa0 = *(const float4*)(xp + 0);  xa1 = *(const float4*)(xp + 4);
    xa2 = *(const float4*)(xp + 8);  xa3 = *(const float4*)(xp + 12);
    const ushort* wp = WT + (size_t)bcol * NE + bkh;
    wb0 = *(const uint4*)(wp + 0);   wb1 = *(const uint4*)(wp + 8);
    wb2 = *(const uint4*)(wp + 16);  wb3 = *(const uint4*)(wp + 24);
  }

  for (int kstep = 0; kstep < NE; kstep += 64) {
    __syncthreads();
    {
      uint4 a0, a1;
      a0.x = cvtpk(xa0.x, xa0.y); a0.y = cvtpk(xa0.z, xa0.w);
      a0.z = cvtpk(xa1.x, xa1.y); a0.w = cvtpk(xa1.z, xa1.w);
      a1.x = cvtpk(xa2.x, xa2.y); a1.y = cvtpk(xa2.z, xa2.w);
      a1.z = cvtpk(xa3.x, xa3.y); a1.w = cvtpk(xa3.z, xa3.w);
      const int swa = (arow & 7) << 4;
      *(uint4*)(As + arow * 128 + ((akq * 2) ^ swa)) = a0;
      *(uint4*)(As + arow * 128 + ((akq * 2 + 16) ^ swa)) = a1;
      const int swb = (bcol & 7) << 4;
      *(uint4*)(Bs + bcol * 128 + ((bkh * 2) ^ swb)) = wb0;
      *(uint4*)(Bs + bcol * 128 + ((bkh * 2 + 16) ^ swb)) = wb1;
      *(uint4*)(Bs + bcol * 128 + ((bkh * 2 + 32) ^ swb)) = wb2;
      *(uint4*)(Bs + bcol * 128 + ((bkh * 2 + 48) ^ swb)) = wb3;
    }
    __syncthreads();
    {
      const int kn = (kstep + 64 < NE) ? kstep + 64 : kstep;
      const float* xp = x + (rbase + arow) * NE + kn + akq;
      xa0 = *(const float4*)(xp + 0);  xa1 = *(const float4*)(xp + 4);
      xa2 = *(const float4*)(xp + 8);  xa3 = *(const float4*)(xp + 12);
      const ushort* wp = WT + (size_t)bcol * NE + kn + bkh;
      wb0 = *(const uint4*)(wp + 0);   wb1 = *(const uint4*)(wp + 8);
      wb2 = *(const uint4*)(wp + 16);  wb3 = *(const uint4*)(wp + 24);
    }
#pragma unroll
    for (int ks = 0; ks < 2; ++ks) {
      s16x8 af[2];
#pragma unroll
      for (int mt = 0; mt < 2; ++mt) {
        const int row = wr * 32 + mt * 16 + lm;
        af[mt] = *(const s16x8*)(As + row * 128 + ((ks * 64 + lg * 16) ^ ((row & 7) << 4)));
      }
#pragma unroll
      for (int nt = 0; nt < 4; ++nt) {
        const int col = wc * 64 + nt * 16 + lm;
        s16x8 bf = *(const s16x8*)(Bs + col * 128 + ((ks * 64 + lg * 16) ^ ((col & 7) << 4)));
#pragma unroll
        for (int mt = 0; mt < 2; ++mt)
          acc[mt][nt] = __builtin_amdgcn_mfma_f32_16x16x32_bf16(af[mt], bf, acc[mt][nt], 0, 0, 0);
      }
    }
  }
#pragma unroll
  for (int nt = 0; nt < 4; ++nt) {
    const int col = wc * 64 + nt * 16 + lm;
    ushort* dst = (col < DD) ? Qo : Ko;
    const int c = col & 63;
#pragma unroll
    for (int mt = 0; mt < 2; ++mt)
#pragma unroll
      for (int r = 0; r < 4; ++r) {
        const size_t row = rbase + wr * 32 + mt * 16 + 4 * lg + r;
        dst[row * DD + c] = f2bf(acc[mt][nt][r]);
      }
  }
}

// ---- MFMA flash attention, exp2-domain, defer-max, split-K ------------------
__global__ __launch_bounds__(256) void attn_kernel(
    const ushort* __restrict__ Qg, const ushort* __restrict__ Kg,
    float* __restrict__ PO, float* __restrict__ ML, float* __restrict__ Od,
    int S) {
  __shared__ __align__(16) char smem[32768];
  char* Kl  = smem;           // 8KB [64 keys][128B] swizzled
  char* KTl = smem + 8192;    // 8KB [64 d][128B]   swizzled (K^T == V^T)
  char* Pl  = smem + 16384;   // 4 x 4KB per-wave P [32 q][128B]

  const int t = threadIdx.x;
  const int w = t >> 6, l = t & 63;
  const int lm = l & 15, lg = l >> 4;
  int idx = blockIdx.x;
  const int s = idx % S; idx /= S;
  const int pr = idx & 15;
  const int b = idx >> 4;
  const size_t bbase = (size_t)b * TT;
  char* Pw = Pl + w * 4096;

  const int rp = t >> 3;    // 0..31 key rowpair
  const int dblk = t & 7;   // 0..7
  // hoisted LDS staging pointers (invariant across chunks)
  const int r0 = 2 * rp, r1 = r0 + 1;
  char* const pKl0 = Kl + r0 * 128 + ((dblk * 16) ^ ((r0 & 7) << 4));
  char* const pKl1 = Kl + r1 * 128 + ((dblk * 16) ^ ((r1 & 7) << 4));
  char* pKT[8];
#pragma unroll
  for (int j = 0; j < 8; ++j) {
    const int d = dblk * 8 + j;
    pKT[j] = KTl + d * 128 + ((rp * 4) ^ KTSWZ(d));
  }

  for (int pass = 0; pass < 2; ++pass) {
    const int tile = pass ? (31 - pr) : pr;
    const int qwb = tile * 128 + w * 32;
    const int nc = 2 * tile + 2;
    const int c0 = (s * nc) / S, c1 = ((s + 1) * nc) / S;

    s16x8 qf[2][2];
#pragma unroll
    for (int qi = 0; qi < 2; ++qi)
#pragma unroll
      for (int ks = 0; ks < 2; ++ks)
        qf[qi][ks] = *(const s16x8*)(Qg + (bbase + qwb + qi * 16 + lm) * DD + ks * 32 + lg * 8);

    float mrun[2] = {-1e30f, -1e30f};
    float lrun[2] = {0.f, 0.f};
    f32x4 oacc[2][4];
#pragma unroll
    for (int qi = 0; qi < 2; ++qi)
#pragma unroll
      for (int dt = 0; dt < 4; ++dt) oacc[qi][dt] = (f32x4)0.f;

    uint4 ra, rb;
    {
      const int cc = (c0 < nc) ? c0 : nc - 1;
      const ushort* src = Kg + (bbase + cc * 64 + 2 * rp) * DD + dblk * 8;
      ra = *(const uint4*)src;
      rb = *(const uint4*)(src + DD);
    }

    for (int c = c0; c < c1; ++c) {
      const int kb = c * 64;
      __syncthreads();
      {  // stage chunk c from prefetched regs (row-major + word-packed transpose)
        *(uint4*)pKl0 = ra;
        *(uint4*)pKl1 = rb;
        const uint wa[4] = {ra.x, ra.y, ra.z, ra.w};
        const uint wb[4] = {rb.x, rb.y, rb.z, rb.w};
#pragma unroll
        for (int jw = 0; jw < 4; ++jw) {
          const uint lo = (wa[jw] & 0xFFFFu) | (wb[jw] << 16);
          const uint hi = (wa[jw] >> 16) | (wb[jw] & 0xFFFF0000u);
          *(uint*)pKT[2 * jw]     = lo;
          *(uint*)pKT[2 * jw + 1] = hi;
        }
      }
      __syncthreads();
      {  // prefetch chunk c+1 (clamped)
        const int cn = (c + 1 < c1) ? (c + 1) : (nc - 1);
        const ushort* src = Kg + (bbase + cn * 64 + 2 * rp) * DD + dblk * 8;
        ra = *(const uint4*)src;
        rb = *(const uint4*)(src + DD);
      }

      const bool act0 = (kb <= qwb + 15);
      const bool act1 = (kb <= qwb + 31);
      if (!act1) continue;

      // ---- S^T = K . Q
      f32x4 sa[2][4];
#pragma unroll
      for (int qi = 0; qi < 2; ++qi)
#pragma unroll
        for (int kt = 0; kt < 4; ++kt) sa[qi][kt] = (f32x4)0.f;
      __builtin_amdgcn_s_setprio(1);
#pragma unroll
      for (int ks = 0; ks < 2; ++ks) {
#pragma unroll
        for (int kt = 0; kt < 4; ++kt) {
          const int key = kt * 16 + lm;
          s16x8 af = *(const s16x8*)(Kl + key * 128 + ((ks * 64 + lg * 16) ^ ((key & 7) << 4)));
          if (act0)
            sa[0][kt] = __builtin_amdgcn_mfma_f32_16x16x32_bf16(af, qf[0][ks], sa[0][kt], 0, 0, 0);
          sa[1][kt] = __builtin_amdgcn_mfma_f32_16x16x32_bf16(af, qf[1][ks], sa[1][kt], 0, 0, 0);
        }
      }
      __builtin_amdgcn_s_setprio(0);

      // ---- mask + online softmax (exp2 domain, defer-max) + P pack
#pragma unroll
      for (int qi = 0; qi < 2; ++qi) {
        const bool act = qi ? act1 : act0;
        if (!act) continue;
        const int qg = qwb + qi * 16 + lm;
        if (kb + 63 > qwb + qi * 16) {
#pragma unroll
          for (int kt = 0; kt < 4; ++kt) {
            const int key0 = kb + kt * 16 + 4 * lg;
#pragma unroll
            for (int r = 0; r < 4; ++r)
              if (key0 + r > qg) sa[qi][kt][r] = -1e30f;
          }
        }
        float mc = -1e30f;
#pragma unroll
        for (int kt = 0; kt < 4; ++kt)
#pragma unroll
          for (int r = 0; r < 4; ++r) mc = fmaxf(mc, sa[qi][kt][r]);
        mc = fmaxf(mc, __shfl_xor(mc, 16));
        mc = fmaxf(mc, __shfl_xor(mc, 32));
        if (__any(mc > mrun[qi] + 8.f)) {   // defer-max: rescale only on growth
          const float mn = fmaxf(mrun[qi], mc);
          const float corr = EXP2(mrun[qi] - mn);
          lrun[qi] *= corr;
#pragma unroll
          for (int dt = 0; dt < 4; ++dt) oacc[qi][dt] *= corr;
          mrun[qi] = mn;
        }
        const float mn = mrun[qi];
        float ps = 0.f;
        char* const Pq = Pw + (qi * 16 + lm) * 128;
        const int swp = (lm & 7) << 4;
#pragma unroll
        for (int kt = 0; kt < 4; ++kt) {
          float pv[4];
#pragma unroll
          for (int r = 0; r < 4; ++r) {
            pv[r] = EXP2(sa[qi][kt][r] - mn);  // masked (-1e30) underflows to 0
            ps += pv[r];
          }
          const int off = kt * 32 + lg * 8;
          *(uint*)(Pq + (off ^ swp))       = cvtpk(pv[0], pv[1]);
          *(uint*)(Pq + ((off + 4) ^ swp)) = cvtpk(pv[2], pv[3]);
        }
        ps += __shfl_xor(ps, 16);
        ps += __shfl_xor(ps, 32);
        lrun[qi] += ps;
      }

      // ---- O^T += V^T . P^T  (V == K)
#pragma unroll
      for (int ks = 0; ks < 2; ++ks) {
        s16x8 pf0 = {}, pf1 = {};
        if (act0) pf0 = *(const s16x8*)(Pw + lm * 128 + ((ks * 64 + lg * 16) ^ ((lm & 7) << 4)));
        if (act1) pf1 = *(const s16x8*)(Pw + (16 + lm) * 128 + ((ks * 64 + lg * 16) ^ ((lm & 7) << 4)));
        __builtin_amdgcn_s_setprio(1);
#pragma unroll
        for (int dt = 0; dt < 4; ++dt) {
          const int d = dt * 16 + lm;
          s16x8 vf = *(const s16x8*)(KTl + d * 128 + ((ks * 64 + lg * 16) ^ KTSWZ(d)));
          if (act0) oacc[0][dt] = __builtin_amdgcn_mfma_f32_16x16x32_bf16(vf, pf0, oacc[0][dt], 0, 0, 0);
          if (act1) oacc[1][dt] = __builtin_amdgcn_mfma_f32_16x16x32_bf16(vf, pf1, oacc[1][dt], 0, 0, 0);
        }
        __builtin_amdgcn_s_setprio(0);
      }
    }

    // ---- epilogue
    if (S == 1) {
#pragma unroll
      for (int qi = 0; qi < 2; ++qi) {
        const size_t qrow = bbase + qwb + qi * 16 + lm;
        const float inv = 1.f / lrun[qi];
#pragma unroll
        for (int dt = 0; dt < 4; ++dt) {
          f32x4 v = oacc[qi][dt] * inv;
          *(f32x4*)(Od + qrow * DD + dt * 16 + 4 * lg) = v;
        }
      }
    } else {
#pragma unroll
      for (int qi = 0; qi < 2; ++qi) {
        const size_t prow = ((size_t)s * BB + b) * TT + qwb + qi * 16 + lm;
#pragma unroll
        for (int dt = 0; dt < 4; ++dt)
          *(f32x4*)(PO + prow * DD + dt * 16 + 4 * lg) = oacc[qi][dt];
        if (lg == 0) {
          ML[prow * 2] = mrun[qi];
          ML[prow * 2 + 1] = lrun[qi];
        }
      }
    }
  }
}

// ---- merge S partials (exp2 domain) -----------------------------------------
__global__ __launch_bounds__(256) void merge_kernel(
    const float* __restrict__ PO, const float* __restrict__ ML,
    float* __restrict__ O, int S) {
  const int flat = blockIdx.x * 256 + threadIdx.x;
  const int q = flat >> 4;
  const int d0 = (flat & 15) * 4;
  float mt = -1e30f;
  for (int s = 0; s < S; ++s)
    mt = fmaxf(mt, ML[((size_t)s * BB * TT + q) * 2]);
  float lsum = 0.f;
  f32x4 acc = (f32x4)0.f;
  for (int s = 0; s < S; ++s) {
    const size_t prow = (size_t)s * BB * TT + q;
    const float m = ML[prow * 2], lv = ML[prow * 2 + 1];
    const float wgt = EXP2(m - mt);
    lsum = fmaf(wgt, lv, lsum);
    const f32x4 po = *(const f32x4*)(PO + prow * DD + d0);
#pragma unroll
    for (int i = 0; i < 4; ++i) acc[i] = fmaf(wgt, po[i], acc[i]);
  }
  const float inv = 1.f / lsum;
#pragma unroll
  for (int i = 0; i < 4; ++i) acc[i] *= inv;
  *(f32x4*)(O + (size_t)q * DD + d0) = acc;
}

extern "C" void kernel_launch(void* const* d_in, const int* in_sizes, int n_in,
                              void* d_out, int out_size, void* d_ws, size_t ws_size,
                              hipStream_t stream) {
  const float* x  = (const float*)d_in[0];
  const float* wq = (const float*)d_in[1];
  const float* wk = (const float*)d_in[2];
  // d_in[3] (w_v) unused: reference computes v with w_k.
  float* out = (float*)d_out;

  const size_t rows = (size_t)BB * TT;         // 32768
  ushort* WT   = (ushort*)d_ws;                // 128 KB
  ushort* Qbuf = WT + (size_t)128 * NE;        // 4 MB
  ushort* Kbuf = Qbuf + rows * DD;             // 4 MB
  char*  after = (char*)(Kbuf + rows * DD);
  const size_t used = (size_t)(after - (char*)d_ws);
  const size_t per  = rows * 2 * 4 + rows * DD * 4;  // ML + PO per split
  int S = 1;
  if (used + 8 * per <= ws_size) S = 8;
  else if (used + 4 * per <= ws_size) S = 4;
  else if (used + 2 * per <= ws_size) S = 2;
  float* ML = (float*)after;
  float* PO = ML + (size_t)S * rows * 2;

  prep_kernel<<<dim3(256), dim3(256), 0, stream>>>(wq, wk, WT);
  proj_kernel<<<dim3(512), dim3(256), 0, stream>>>(x, WT, Qbuf, Kbuf);
  attn_kernel<<<dim3(BB * 16 * S), dim3(256), 0, stream>>>(Qbuf, Kbuf, PO, ML, out, S);
  if (S > 1)
    merge_kernel<<<dim3(2048), dim3(256), 0, stream>>>(PO, ML, out, S);
}

// Round 5
// 83.465 us; speedup vs baseline: 1.0552x; 1.0552x over previous
//
#include <hip/hip_runtime.h>
#include <math.h>

#define BB 8
#define TT 4096
#define NE 512
#define DD 64

using f32x4 = __attribute__((ext_vector_type(4))) float;
using s16x8 = __attribute__((ext_vector_type(8))) short;

#define EXP2 __builtin_amdgcn_exp2f

__device__ __forceinline__ ushort f2bf(float f) {
  uint u = __builtin_bit_cast(uint, f);
  u += 0x7fffu + ((u >> 16) & 1u);
  return (ushort)(u >> 16);
}
__device__ __forceinline__ uint cvtpk(float lo, float hi) {
  uint r;
  asm("v_cvt_pk_bf16_f32 %0, %1, %2" : "=v"(r) : "v"(lo), "v"(hi));
  return r;
}
__device__ __forceinline__ void pl32swap(uint& a, uint& b) {
  asm("v_permlane32_swap_b32 %0, %1" : "+v"(a), "+v"(b));
}
__device__ __forceinline__ void pl16swap(uint& a, uint& b) {
  asm("v_permlane16_swap_b32 %0, %1" : "+v"(a), "+v"(b));
}

#define KTSWZ(d) ((((d) ^ ((d) >> 3)) & 7) << 4)

// ---- prep: WT[col][k] bf16; col<64 = wq * 0.125*log2(e)  (exp2 domain), else wk
__global__ __launch_bounds__(256) void prep_kernel(
    const float* __restrict__ wq, const float* __restrict__ wk,
    ushort* __restrict__ WT) {
  const int i = blockIdx.x * 256 + threadIdx.x;  // 65536
  const int col = i & 127, k = i >> 7;
  const float v = (col < DD) ? wq[(size_t)k * DD + col] * 0.18033688f
                             : wk[(size_t)k * DD + (col - DD)];
  WT[(size_t)col * NE + k] = f2bf(v);
}

// ---- proj: bf16 MFMA GEMM, out = x @ [wq*s | wk] ----------------------------
__global__ __launch_bounds__(256) void proj_kernel(
    const float* __restrict__ x, const ushort* __restrict__ WT,
    ushort* __restrict__ Qo, ushort* __restrict__ Ko) {
  __shared__ __align__(16) char smem[24576];
  char* As = smem;          // [64 rows][128B] swizzled
  char* Bs = smem + 8192;   // [128 cols][128B] swizzled
  const int t = threadIdx.x;
  const int w = t >> 6, l = t & 63;
  const int lm = l & 15, lg = l >> 4;
  const int wr = w >> 1, wc = w & 1;
  const size_t rbase = (size_t)blockIdx.x * 64;

  const int arow = t >> 2, akq = (t & 3) * 16;
  const int bcol = t >> 1, bkh = (t & 1) * 32;

  f32x4 acc[2][4];
#pragma unroll
  for (int mt = 0; mt < 2; ++mt)
#pragma unroll
    for (int nt = 0; nt < 4; ++nt) acc[mt][nt] = (f32x4)0.f;

  float4 xa0, xa1, xa2, xa3;
  uint4 wb0, wb1, wb2, wb3;
  {
    const float* xp = x + (rbase + arow) * NE + akq;
    xa0 = *(const float4*)(xp + 0);  xa1 = *(const float4*)(xp + 4);
    xa2 = *(const float4*)(xp + 8);  xa3 = *(const float4*)(xp + 12);
    const ushort* wp = WT + (size_t)bcol * NE + bkh;
    wb0 = *(const uint4*)(wp + 0);   wb1 = *(const uint4*)(wp + 8);
    wb2 = *(const uint4*)(wp + 16);  wb3 = *(const uint4*)(wp + 24);
  }

  for (int kstep = 0; kstep < NE; kstep += 64) {
    __syncthreads();
    {
      uint4 a0, a1;
      a0.x = cvtpk(xa0.x, xa0.y); a0.y = cvtpk(xa0.z, xa0.w);
      a0.z = cvtpk(xa1.x, xa1.y); a0.w = cvtpk(xa1.z, xa1.w);
      a1.x = cvtpk(xa2.x, xa2.y); a1.y = cvtpk(xa2.z, xa2.w);
      a1.z = cvtpk(xa3.x, xa3.y); a1.w = cvtpk(xa3.z, xa3.w);
      const int swa = (arow & 7) << 4;
      *(uint4*)(As + arow * 128 + ((akq * 2) ^ swa)) = a0;
      *(uint4*)(As + arow * 128 + ((akq * 2 + 16) ^ swa)) = a1;
      const int swb = (bcol & 7) << 4;
      *(uint4*)(Bs + bcol * 128 + ((bkh * 2) ^ swb)) = wb0;
      *(uint4*)(Bs + bcol * 128 + ((bkh * 2 + 16) ^ swb)) = wb1;
      *(uint4*)(Bs + bcol * 128 + ((bkh * 2 + 32) ^ swb)) = wb2;
      *(uint4*)(Bs + bcol * 128 + ((bkh * 2 + 48) ^ swb)) = wb3;
    }
    __syncthreads();
    {
      const int kn = (kstep + 64 < NE) ? kstep + 64 : kstep;
      const float* xp = x + (rbase + arow) * NE + kn + akq;
      xa0 = *(const float4*)(xp + 0);  xa1 = *(const float4*)(xp + 4);
      xa2 = *(const float4*)(xp + 8);  xa3 = *(const float4*)(xp + 12);
      const ushort* wp = WT + (size_t)bcol * NE + kn + bkh;
      wb0 = *(const uint4*)(wp + 0);   wb1 = *(const uint4*)(wp + 8);
      wb2 = *(const uint4*)(wp + 16);  wb3 = *(const uint4*)(wp + 24);
    }
#pragma unroll
    for (int ks = 0; ks < 2; ++ks) {
      s16x8 af[2];
#pragma unroll
      for (int mt = 0; mt < 2; ++mt) {
        const int row = wr * 32 + mt * 16 + lm;
        af[mt] = *(const s16x8*)(As + row * 128 + ((ks * 64 + lg * 16) ^ ((row & 7) << 4)));
      }
#pragma unroll
      for (int nt = 0; nt < 4; ++nt) {
        const int col = wc * 64 + nt * 16 + lm;
        s16x8 bf = *(const s16x8*)(Bs + col * 128 + ((ks * 64 + lg * 16) ^ ((col & 7) << 4)));
#pragma unroll
        for (int mt = 0; mt < 2; ++mt)
          acc[mt][nt] = __builtin_amdgcn_mfma_f32_16x16x32_bf16(af[mt], bf, acc[mt][nt], 0, 0, 0);
      }
    }
  }
#pragma unroll
  for (int nt = 0; nt < 4; ++nt) {
    const int col = wc * 64 + nt * 16 + lm;
    ushort* dst = (col < DD) ? Qo : Ko;
    const int c = col & 63;
#pragma unroll
    for (int mt = 0; mt < 2; ++mt)
#pragma unroll
      for (int r = 0; r < 4; ++r) {
        const size_t row = rbase + wr * 32 + mt * 16 + 4 * lg + r;
        dst[row * DD + c] = f2bf(acc[mt][nt][r]);
      }
  }
}

// ---- MFMA flash attention: tile-proportional split-K, in-register P ---------
// Grid: BB * 144. Block (b, tile, s): tile 0..31 (128 q rows), split s < k
// where k = tile/4 + 1. Tiles 0..3 (k==1) write output directly.
__global__ __launch_bounds__(256, 4) void attn_kernel(
    const ushort* __restrict__ Qg, const ushort* __restrict__ Kg,
    float* __restrict__ PO, float* __restrict__ ML, float* __restrict__ Od) {
  __shared__ __align__(16) char smem[16384];
  char* Kl  = smem;           // 8KB [64 keys][128B] swizzled (S^T A-operand)
  char* KTl = smem + 8192;    // 8KB [64 d][128B]   swizzled (K^T == V^T)

  const int t = threadIdx.x;
  const int w = t >> 6, l = t & 63;
  const int lm = l & 15, lg = l >> 4;

  // decode block -> (b, tile, s); group k has tiles 4(k-1)..4k-1, k splits each
  const int bid = blockIdx.x;
  const int b = bid / 144;
  const int id2 = bid - b * 144;
  int k = 1;
  while (k < 8 && id2 >= 2 * k * (k + 1)) ++k;
  const int r_ = id2 - 2 * k * (k - 1);
  const int tq_ = r_ / k;
  const int tile = 4 * (k - 1) + tq_;
  const int s = r_ - tq_ * k;
  const int nc = 2 * tile + 2;
  const int c0 = (s * nc) / k, c1 = ((s + 1) * nc) / k;

  const size_t bbase = (size_t)b * TT;
  const int qwb = tile * 128 + w * 32;

  const int rp = t >> 3;    // 0..31 key rowpair
  const int dblk = t & 7;   // 0..7
  const int r0 = 2 * rp, r1 = r0 + 1;
  char* const pKl0 = Kl + r0 * 128 + ((dblk * 16) ^ ((r0 & 7) << 4));
  char* const pKl1 = Kl + r1 * 128 + ((dblk * 16) ^ ((r1 & 7) << 4));
  char* pKT[8];
#pragma unroll
  for (int j = 0; j < 8; ++j) {
    const int d = dblk * 8 + j;
    pKT[j] = KTl + d * 128 + ((rp * 4) ^ KTSWZ(d));
  }

  s16x8 qf[2][2];
#pragma unroll
  for (int qi = 0; qi < 2; ++qi)
#pragma unroll
    for (int ks = 0; ks < 2; ++ks)
      qf[qi][ks] = *(const s16x8*)(Qg + (bbase + qwb + qi * 16 + lm) * DD + ks * 32 + lg * 8);

  float mrun[2] = {-1e30f, -1e30f};
  float lrun[2] = {0.f, 0.f};
  f32x4 oacc[2][4];
#pragma unroll
  for (int qi = 0; qi < 2; ++qi)
#pragma unroll
    for (int dt = 0; dt < 4; ++dt) oacc[qi][dt] = (f32x4)0.f;

  uint4 ra, rb;
  {
    const ushort* src = Kg + (bbase + c0 * 64 + r0) * DD + dblk * 8;
    ra = *(const uint4*)src;
    rb = *(const uint4*)(src + DD);
  }

  for (int c = c0; c < c1; ++c) {
    const int kb = c * 64;
    __syncthreads();
    {  // stage chunk c from prefetched regs (row-major + word-packed transpose)
      *(uint4*)pKl0 = ra;
      *(uint4*)pKl1 = rb;
      const uint wa[4] = {ra.x, ra.y, ra.z, ra.w};
      const uint wb[4] = {rb.x, rb.y, rb.z, rb.w};
#pragma unroll
      for (int jw = 0; jw < 4; ++jw) {
        const uint lo = (wa[jw] & 0xFFFFu) | (wb[jw] << 16);
        const uint hi = (wa[jw] >> 16) | (wb[jw] & 0xFFFF0000u);
        *(uint*)pKT[2 * jw]     = lo;
        *(uint*)pKT[2 * jw + 1] = hi;
      }
    }
    __syncthreads();
    {  // prefetch chunk c+1 (clamped)
      const int cn = (c + 1 < c1) ? (c + 1) : (nc - 1);
      const ushort* src = Kg + (bbase + cn * 64 + r0) * DD + dblk * 8;
      ra = *(const uint4*)src;
      rb = *(const uint4*)(src + DD);
    }

    if (kb > qwb + 31) continue;  // wave fully masked (barriers already passed)

    // ---- S^T = K . Q
    f32x4 sa[2][4];
#pragma unroll
    for (int qi = 0; qi < 2; ++qi)
#pragma unroll
      for (int kt = 0; kt < 4; ++kt) sa[qi][kt] = (f32x4)0.f;
    __builtin_amdgcn_s_setprio(1);
#pragma unroll
    for (int ks = 0; ks < 2; ++ks) {
#pragma unroll
      for (int kt = 0; kt < 4; ++kt) {
        const int key = kt * 16 + lm;
        s16x8 af = *(const s16x8*)(Kl + key * 128 + ((ks * 64 + lg * 16) ^ ((key & 7) << 4)));
        sa[0][kt] = __builtin_amdgcn_mfma_f32_16x16x32_bf16(af, qf[0][ks], sa[0][kt], 0, 0, 0);
        sa[1][kt] = __builtin_amdgcn_mfma_f32_16x16x32_bf16(af, qf[1][ks], sa[1][kt], 0, 0, 0);
      }
    }
    __builtin_amdgcn_s_setprio(0);

    // ---- mask + online softmax (exp2, defer-max) + in-register P fragments
    uint fragP[2][2][4];  // [qi][ks][word]
#pragma unroll
    for (int qi = 0; qi < 2; ++qi) {
      const int qg = qwb + qi * 16 + lm;
      if (kb + 63 > qwb + qi * 16) {  // diagonal chunk: apply causal mask
#pragma unroll
        for (int kt = 0; kt < 4; ++kt) {
          const int key0 = kb + kt * 16 + 4 * lg;
#pragma unroll
          for (int r = 0; r < 4; ++r)
            if (key0 + r > qg) sa[qi][kt][r] = -1e30f;
        }
      }
      float mc = -1e30f;
#pragma unroll
      for (int kt = 0; kt < 4; ++kt)
#pragma unroll
        for (int r = 0; r < 4; ++r) mc = fmaxf(mc, sa[qi][kt][r]);
      mc = fmaxf(mc, __shfl_xor(mc, 16));
      mc = fmaxf(mc, __shfl_xor(mc, 32));
      if (__any(mc > mrun[qi] + 8.f)) {   // defer-max: rescale only on growth
        const float mn = fmaxf(mrun[qi], mc);
        const float corr = EXP2(mrun[qi] - mn);
        lrun[qi] *= corr;
#pragma unroll
        for (int dt = 0; dt < 4; ++dt) oacc[qi][dt] *= corr;
        mrun[qi] = mn;
      }
      const float mn = mrun[qi];
      float ps = 0.f;
      uint pk[4][2];
#pragma unroll
      for (int kt = 0; kt < 4; ++kt) {
        float pv[4];
#pragma unroll
        for (int r = 0; r < 4; ++r) {
          pv[r] = EXP2(sa[qi][kt][r] - mn);  // masked (-1e30) underflows to 0
          ps += pv[r];
        }
        pk[kt][0] = cvtpk(pv[0], pv[1]);
        pk[kt][1] = cvtpk(pv[2], pv[3]);
      }
      ps += __shfl_xor(ps, 16);
      ps += __shfl_xor(ps, 32);
      lrun[qi] += ps;
      // 4-lane-group transpose: (keys in regs, q in lanes) -> PV B-operand
#pragma unroll
      for (int ks = 0; ks < 2; ++ks) {
        uint R0 = pk[2 * ks][0], R1 = pk[2 * ks][1];
        uint R2 = pk[2 * ks + 1][0], R3 = pk[2 * ks + 1][1];
        pl32swap(R0, R2); pl32swap(R1, R3);
        pl16swap(R0, R2); pl16swap(R1, R3);
        fragP[qi][ks][0] = R0; fragP[qi][ks][1] = R1;
        fragP[qi][ks][2] = R2; fragP[qi][ks][3] = R3;
      }
    }

    // ---- O^T += V^T . P^T  (V == K; vf shared across q-frags)
    __builtin_amdgcn_s_setprio(1);
#pragma unroll
    for (int ks = 0; ks < 2; ++ks) {
      union { uint u[4]; s16x8 v; } p0, p1;
#pragma unroll
      for (int j = 0; j < 4; ++j) { p0.u[j] = fragP[0][ks][j]; p1.u[j] = fragP[1][ks][j]; }
#pragma unroll
      for (int dt = 0; dt < 4; ++dt) {
        const int d = dt * 16 + lm;
        s16x8 vf = *(const s16x8*)(KTl + d * 128 + ((ks * 64 + lg * 16) ^ KTSWZ(d)));
        oacc[0][dt] = __builtin_amdgcn_mfma_f32_16x16x32_bf16(vf, p0.v, oacc[0][dt], 0, 0, 0);
        oacc[1][dt] = __builtin_amdgcn_mfma_f32_16x16x32_bf16(vf, p1.v, oacc[1][dt], 0, 0, 0);
      }
    }
    __builtin_amdgcn_s_setprio(0);
  }

  // ---- epilogue: direct normalized output (k==1) or unnormalized partials
  if (k == 1) {
#pragma unroll
    for (int qi = 0; qi < 2; ++qi) {
      const size_t qrow = bbase + qwb + qi * 16 + lm;
      const float inv = 1.f / lrun[qi];
#pragma unroll
      for (int dt = 0; dt < 4; ++dt) {
        f32x4 v = oacc[qi][dt] * inv;
        *(f32x4*)(Od + qrow * DD + dt * 16 + 4 * lg) = v;
      }
    }
  } else {
#pragma unroll
    for (int qi = 0; qi < 2; ++qi) {
      const size_t prow = ((size_t)s * BB + b) * TT + qwb + qi * 16 + lm;
#pragma unroll
      for (int dt = 0; dt < 4; ++dt)
        *(f32x4*)(PO + prow * DD + dt * 16 + 4 * lg) = oacc[qi][dt];
      if (lg == 0) {
        ML[prow * 2] = mrun[qi];
        ML[prow * 2 + 1] = lrun[qi];
      }
    }
  }
}

// ---- merge variable-S partials (rows with tile >= 4 only) -------------------
__global__ __launch_bounds__(256) void merge_kernel(
    const float* __restrict__ PO, const float* __restrict__ ML,
    float* __restrict__ O) {
  const int flat = blockIdx.x * 256 + threadIdx.x;
  const int qo = flat >> 4;                  // 0..28671
  const int d0 = (flat & 15) * 4;
  const int b = qo / 3584;
  const int qrow = 512 + (qo - b * 3584);    // tiles 4..31
  const int St = (qrow >> 9) + 1;            // tile/4 + 1 = qrow/512 + 1
  float mt = -1e30f;
  for (int s = 0; s < St; ++s)
    mt = fmaxf(mt, ML[(((size_t)s * BB + b) * TT + qrow) * 2]);
  float lsum = 0.f;
  f32x4 acc = (f32x4)0.f;
  for (int s = 0; s < St; ++s) {
    const size_t prow = ((size_t)s * BB + b) * TT + qrow;
    const float m = ML[prow * 2], lv = ML[prow * 2 + 1];
    const float wgt = EXP2(m - mt);
    lsum = fmaf(wgt, lv, lsum);
    const f32x4 po = *(const f32x4*)(PO + prow * DD + d0);
#pragma unroll
    for (int i = 0; i < 4; ++i) acc[i] = fmaf(wgt, po[i], acc[i]);
  }
  const float inv = 1.f / lsum;
#pragma unroll
  for (int i = 0; i < 4; ++i) acc[i] *= inv;
  *(f32x4*)(O + ((size_t)b * TT + qrow) * DD + d0) = acc;
}

extern "C" void kernel_launch(void* const* d_in, const int* in_sizes, int n_in,
                              void* d_out, int out_size, void* d_ws, size_t ws_size,
                              hipStream_t stream) {
  const float* x  = (const float*)d_in[0];
  const float* wq = (const float*)d_in[1];
  const float* wk = (const float*)d_in[2];
  // d_in[3] (w_v) unused: reference computes v with w_k.
  float* out = (float*)d_out;

  const size_t rows = (size_t)BB * TT;         // 32768
  ushort* WT   = (ushort*)d_ws;                // 128 KB
  ushort* Qbuf = WT + (size_t)128 * NE;        // 4 MB
  ushort* Kbuf = Qbuf + rows * DD;             // 4 MB
  float* ML = (float*)(Kbuf + rows * DD);      // 8 slots x 256KB
  float* PO = ML + (size_t)8 * rows * 2;       // 8 slots x 8MB

  prep_kernel<<<dim3(256), dim3(256), 0, stream>>>(wq, wk, WT);
  proj_kernel<<<dim3(512), dim3(256), 0, stream>>>(x, WT, Qbuf, Kbuf);
  attn_kernel<<<dim3(BB * 144), dim3(256), 0, stream>>>(Qbuf, Kbuf, PO, ML, out);
  merge_kernel<<<dim3(1792), dim3(256), 0, stream>>>(PO, ML, out);
}